// Round 2
// baseline (143.190 us; speedup 1.0000x reference)
//
#include <hip/hip_runtime.h>

// Problem: x[2048][32][2] fp32 -> pe[2048][32][512] fp32
//   pe[i,b,2p]   = sin(x[i,b,0] * exp(p * -ln(1e4)/256))
//   pe[i,b,2p+1] = cos(x[i,b,1] * exp(p * -ln(1e4)/256))
//
// Write-BW-bound: 134 MB out vs 0.5 MB in. One thread per float4 (2 pairs).

#define NUM_ROWS   (2048 * 32)        // (i,b) pairs
#define V4_PER_ROW (512 / 4)          // 128 float4 per row
#define TOTAL_V4   (NUM_ROWS * V4_PER_ROW)

typedef float fvec4 __attribute__((ext_vector_type(4)));   // native vector for nontemporal store

__global__ __launch_bounds__(256) void pe2d_kernel(const float* __restrict__ x,
                                                   float* __restrict__ out) {
    const int idx = blockIdx.x * 256 + threadIdx.x;   // one float4 of output
    const int row = idx >> 7;                         // (i,b) row, 128 v4/row
    const int t   = idx & 127;                        // v4 index within row

    // Broadcast load of this row's coords (all 64 lanes of a wave share it).
    const float2 xy = ((const float2*)x)[row];        // {x0, x1}

    const int   p0 = t * 2;                           // first pair index
    const float k  = -0.051905126482615036f;          // -log2(10000)/256
    const float d0 = exp2f(k * (float)p0);
    const float d1 = exp2f(k * (float)(p0 + 1));

    fvec4 r;
    r.x = __sinf(xy.x * d0);
    r.y = __cosf(xy.y * d0);
    r.z = __sinf(xy.x * d1);
    r.w = __cosf(xy.y * d1);

    __builtin_nontemporal_store(r, ((fvec4*)out) + idx);
}

extern "C" void kernel_launch(void* const* d_in, const int* in_sizes, int n_in,
                              void* d_out, int out_size, void* d_ws, size_t ws_size,
                              hipStream_t stream) {
    const float* x = (const float*)d_in[0];
    float* out = (float*)d_out;
    const int blocks = TOTAL_V4 / 256;                // 32768
    pe2d_kernel<<<blocks, 256, 0, stream>>>(x, out);
}

// Round 3
// 131.720 us; speedup vs baseline: 1.0871x; 1.0871x over previous
//
#include <hip/hip_runtime.h>

// Problem: x[2048][32][2] fp32 -> pe[2048][32][512] fp32
//   pe[i,b,2p]   = sin(x[i,b,0] * exp(p * -ln(1e4)/256))
//   pe[i,b,2p+1] = cos(x[i,b,1] * exp(p * -ln(1e4)/256))
//
// Write-BW-bound: 134 MB out, 0.5 MB in.
// R2 lesson: nontemporal stores tanked write BW to ~0.9 TB/s (partial-line
// writes bypass L2 write-combining). Plain dwordx4 stores + 4 stores/thread.

#define NUM_ROWS   (2048 * 32)        // (i,b) pairs
#define V4_PER_ROW (512 / 4)          // 128 float4 per row
#define ROWS_PER_BLOCK 8              // 1024 float4 per block
#define V4_PER_BLOCK (ROWS_PER_BLOCK * V4_PER_ROW)

typedef float fvec4 __attribute__((ext_vector_type(4)));

__global__ __launch_bounds__(256) void pe2d_kernel(const float* __restrict__ x,
                                                   float* __restrict__ out) {
    const int tid  = threadIdx.x;
    const int t    = tid & 127;            // float4 index within a row
    const int r    = tid >> 7;             // 0 or 1: row offset within pair
    const int row0 = blockIdx.x * ROWS_PER_BLOCK;

    // div_term for this thread's channel pair — computed once, reused 4 rows.
    const int   p0 = t * 2;
    const float k  = -0.051905126482615036f;  // -log2(10000)/256
    const float d0 = exp2f(k * (float)p0);
    const float d1 = exp2f(k * (float)(p0 + 1));

    const float2* __restrict__ xv = (const float2*)x;
    fvec4* __restrict__ ov = (fvec4*)out;

    #pragma unroll
    for (int j = 0; j < 4; ++j) {
        const int row = row0 + r + 2 * j;          // wave-uniform
        const float2 xy = xv[row];                 // broadcast load (L1/L2 hit)
        fvec4 o;
        o.x = __sinf(xy.x * d0);
        o.y = __cosf(xy.y * d0);
        o.z = __sinf(xy.x * d1);
        o.w = __cosf(xy.y * d1);
        ov[row * V4_PER_ROW + t] = o;              // contiguous 1 KB per wave
    }
}

extern "C" void kernel_launch(void* const* d_in, const int* in_sizes, int n_in,
                              void* d_out, int out_size, void* d_ws, size_t ws_size,
                              hipStream_t stream) {
    const float* x = (const float*)d_in[0];
    float* out = (float*)d_out;
    const int blocks = NUM_ROWS / ROWS_PER_BLOCK;   // 8192
    pe2d_kernel<<<blocks, 256, 0, stream>>>(x, out);
}